// Round 5
// baseline (205.678 us; speedup 1.0000x reference)
//
#include <hip/hip_runtime.h>
#include <math.h>

#define BSZ 2
#define TSEQ 2048
#define CDIM 1024
#define HNUM 16

typedef __attribute__((ext_vector_type(8))) short bhalf8;
typedef __attribute__((ext_vector_type(4))) short bhalf4;
typedef __attribute__((ext_vector_type(4))) float floatx4;

// fp32 -> bf16 round-to-nearest-even
__device__ __forceinline__ unsigned short f2bf(float f) {
    union { float f; unsigned u; } v;
    v.f = f;
    unsigned r = v.u + 0x7FFFu + ((v.u >> 16) & 1u);
    return (unsigned short)(r >> 16);
}

// async global->LDS, 16 B per lane. lds dest = (wave-uniform base) + lane*16.
typedef __attribute__((address_space(3))) unsigned int lds_u32;
typedef const __attribute__((address_space(1))) unsigned int g_u32;
__device__ __forceinline__ void async_copy16(const void* g, void* l) {
    __builtin_amdgcn_global_load_lds((g_u32*)g, (lds_u32*)l, 16, 0, 0);
}

// ---------------------------------------------------------------------------
// Prepass: fp32 -> bf16 elementwise (x). 8 elements/thread.
// ---------------------------------------------------------------------------
__global__ __launch_bounds__(256) void conv_bf16(
    const float* __restrict__ x, unsigned short* __restrict__ xb)
{
    size_t i = ((size_t)blockIdx.x * 256 + threadIdx.x) * 8;
    float4 a = *(const float4*)(x + i);
    float4 b = *(const float4*)(x + i + 4);
    uint4 o;
    o.x = (unsigned)f2bf(a.x) | ((unsigned)f2bf(a.y) << 16);
    o.y = (unsigned)f2bf(a.z) | ((unsigned)f2bf(a.w) << 16);
    o.z = (unsigned)f2bf(b.x) | ((unsigned)f2bf(b.y) << 16);
    o.w = (unsigned)f2bf(b.z) | ((unsigned)f2bf(b.w) << 16);
    *(uint4*)(xb + i) = o;
}

// ---------------------------------------------------------------------------
// Prepass: W [K,N] fp32 -> Wt [N,K] bf16 (transpose + convert). 32x32 tiles.
// ---------------------------------------------------------------------------
__global__ __launch_bounds__(256) void transpose_bf16(
    const float* __restrict__ W, unsigned short* __restrict__ Wt, int K, int N)
{
    __shared__ float t[32][33];
    const int n0 = blockIdx.x * 32, k0 = blockIdx.y * 32;
    const int tx = threadIdx.x & 31, ty = threadIdx.x >> 5;  // ty 0..7
#pragma unroll
    for (int i = 0; i < 4; ++i)
        t[ty + i * 8][tx] = W[(size_t)(k0 + ty + i * 8) * N + n0 + tx];
    __syncthreads();
#pragma unroll
    for (int i = 0; i < 4; ++i)
        Wt[(size_t)(n0 + ty + i * 8) * K + k0 + tx] = f2bf(t[tx][ty + i * 8]);
}

// ---------------------------------------------------------------------------
// bf16 MFMA GEMM (B^T input) + bias: C[M,N] = A[M,K] @ Bt[N,K]^T + bias[N]
// m97 structure. Blocks with col >= v_start (v_start>=0) write their output
// TRANSPOSED to vt: vt[(row>>11)*1024 + (col-v_start)][row&2047] — this is
// V^T layout [b*1024 + h*64 + d][t] used by the attention kernel.
// ---------------------------------------------------------------------------
template<bool OUT_BF16>
__global__ __launch_bounds__(256) void gemm_bt(
    const unsigned short* __restrict__ A, const unsigned short* __restrict__ Bt,
    const float* __restrict__ bias, void* __restrict__ Cp,
    int M, int N, int K, int v_start, unsigned short* __restrict__ vt)
{
    __shared__ unsigned short As[128 * 32];
    __shared__ unsigned short Bs[128 * 32];

    const int tid   = threadIdx.x;
    const int bm    = blockIdx.y;
    const int bn    = blockIdx.x;
    const int wave  = tid >> 6;
    const int col16 = tid & 15;
    const int quad  = (tid & 63) >> 4;
    const int wm    = (wave >> 1) * 64;
    const int wn    = (wave & 1) * 64;

    const floatx4 vzero = {0.f, 0.f, 0.f, 0.f};
    floatx4 acc[4][4];
#pragma unroll
    for (int i = 0; i < 4; ++i)
#pragma unroll
        for (int j = 0; j < 4; ++j) acc[i][j] = vzero;

    const int gr = tid >> 2;
    const int gk = (tid & 3) * 8;
    const unsigned short* Ab = A  + (size_t)(bm * 128 + gr) * K + gk;
    const unsigned short* Bb = Bt + (size_t)(bn * 128 + gr) * K + gk;
    char* AsB = (char*)As + wave * 1024;
    char* BsB = (char*)Bs + wave * 1024;

    for (int k0 = 0; k0 < K; k0 += 32) {
        __syncthreads();
        async_copy16(Ab + k0,          AsB);
        async_copy16(Ab + 64 * K + k0, AsB + 4096);
        async_copy16(Bb + k0,          BsB);
        async_copy16(Bb + 64 * K + k0, BsB + 4096);
        __syncthreads();

        bhalf8 a[4], b[4];
#pragma unroll
        for (int i = 0; i < 4; ++i)
            a[i] = *(const bhalf8*)&As[(wm + i * 16 + col16) * 32 + quad * 8];
#pragma unroll
        for (int j = 0; j < 4; ++j)
            b[j] = *(const bhalf8*)&Bs[(wn + j * 16 + col16) * 32 + quad * 8];
#pragma unroll
        for (int i = 0; i < 4; ++i)
#pragma unroll
            for (int j = 0; j < 4; ++j)
                acc[i][j] = __builtin_amdgcn_mfma_f32_16x16x32_bf16(a[i], b[j], acc[i][j], 0, 0, 0);
    }

    const int colbase = bn * 128 + wn;
    const bool vpath = (v_start >= 0) && (colbase >= v_start);  // block-uniform
#pragma unroll
    for (int j = 0; j < 4; ++j) {
        int col = colbase + j * 16 + col16;
        float bv = bias[col];
#pragma unroll
        for (int i = 0; i < 4; ++i) {
#pragma unroll
            for (int r = 0; r < 4; ++r) {
                int row = bm * 128 + wm + i * 16 + quad * 4 + r;
                float v = acc[i][j][r] + bv;
                if (vpath) {
                    // V^T: vt[(b*1024 + (col - v_start))][t]
                    size_t vrow = (size_t)((row >> 11) * 1024 + (col - v_start));
                    vt[vrow * 2048 + (row & 2047)] = f2bf(v);
                } else if (OUT_BF16) {
                    ((unsigned short*)Cp)[(size_t)row * N + col] = f2bf(v);
                } else {
                    ((float*)Cp)[(size_t)row * N + col] = v;
                }
            }
        }
    }
}

// ---------------------------------------------------------------------------
// MFMA flash attention v3: transposed scores, async-staged K AND V^T,
// diagonal-tile split (mask only on kb==qb), cheap bf16 pack.
//   S^T = K . Q^T (16x16x32); C-layout of S^T == B-frag of 16x16x16,
//   so P^T feeds O^T = V^T . P^T straight from registers.
// Fixed-shift softmax: p = exp(s/8 - 12); l reduced once at epilogue.
// K LDS image: row*64 + (chunk ^ (row&7))*8   (16-B chunk XOR swizzle)
// Vt LDS image: d*64 + (chunk ^ (d&7))*8      (swizzle applied in the
//   *source address* of the async copy; global vT is plain [d][t])
// ---------------------------------------------------------------------------
__device__ __forceinline__ floatx4 fx4_zero() { floatx4 z = {0.f,0.f,0.f,0.f}; return z; }

template<bool DIAG>
__device__ __forceinline__ void attn_kv_tile(
    int kb,
    const unsigned short* __restrict__ kbase,
    const unsigned short* __restrict__ vtb,
    unsigned short* Ks, unsigned short* Vt,
    const bhalf8* qf, floatx4* oT, float& l_part,
    int tid, int col16, int quad, int qloc)
{
    // p = exp(s*0.125 - 12) = exp2(s*0.18033688 - 17.31234)
    const float C_MUL = 0.125f * 1.44269504f;
    const float C_SUB = 17.31234049f;

    // K staging: lane covers K row (tid>>3), 16-B chunk (tid&7)^(row&7)
    const int krow0 = tid >> 3;                  // 0..31
    const int kcb   = (tid & 7) ^ ((tid >> 3) & 7);
    char* ksb = (char*)Ks + (tid >> 6) * 1024;
    // V staging: lane covers vT row d=(tid>>3), source t-chunk (tid&7)^(d&7)
    const int vc8s  = (tid & 7) ^ ((tid >> 3) & 7);
    char* vsb = (char*)Vt + (tid >> 6) * 1024;

    __syncthreads();   // prior iteration done reading Ks/Vt
    async_copy16(kbase + (size_t)(kb * 64 + krow0) * 3072 + kcb * 8, ksb);
    async_copy16(kbase + (size_t)(kb * 64 + 32 + krow0) * 3072 + kcb * 8, ksb + 4096);
    async_copy16(vtb + (size_t)krow0 * 2048 + kb * 64 + vc8s * 8, vsb);
    async_copy16(vtb + (size_t)(krow0 + 32) * 2048 + kb * 64 + vc8s * 8, vsb + 4096);
    __syncthreads();   // drains vmcnt -> LDS visible

    // ---- S^T = K . Q^T : lane holds S^T[kv=16n+quad*4+r][q=col16] ----
    const int sx = col16 & 7;
    floatx4 s[4];
#pragma unroll
    for (int n = 0; n < 4; ++n) {
        const int row = 16 * n + col16;
        bhalf8 k0 = *(const bhalf8*)&Ks[row * 64 + ((quad ^ sx) * 8)];
        bhalf8 k1 = *(const bhalf8*)&Ks[row * 64 + (((4 + quad) ^ sx) * 8)];
        floatx4 t = __builtin_amdgcn_mfma_f32_16x16x32_bf16(k0, qf[0], fx4_zero(), 0, 0, 0);
        s[n] = __builtin_amdgcn_mfma_f32_16x16x32_bf16(k1, qf[1], t, 0, 0, 0);
    }

    // ---- p = exp2(s*c - c2) [+ mask on DIAG], accumulate l, pack P^T ----
    bhalf4 pb[4];
#pragma unroll
    for (int n = 0; n < 4; ++n) {
        unsigned a[4];
#pragma unroll
        for (int r = 0; r < 4; ++r) {
            float p = exp2f(fmaf(s[n][r], C_MUL, -C_SUB));
            if (DIAG) {
                const int kvloc = 16 * n + quad * 4 + r;
                if (kvloc > qloc) p = 0.f;
            }
            l_part += p;
            a[r] = __float_as_uint(p) + 0x8000u;   // bias-round to bf16
        }
        union { unsigned u[2]; bhalf4 b; } uu;
        uu.u[0] = (a[0] >> 16) | (a[1] & 0xffff0000u);
        uu.u[1] = (a[2] >> 16) | (a[3] & 0xffff0000u);
        pb[n] = uu.b;
    }

    // ---- O^T += V^T . P^T (A-frag b64 reads, swizzled) ----
#pragma unroll
    for (int n = 0; n < 4; ++n) {
        const int ch = 2 * n + (quad >> 1);
#pragma unroll
        for (int dt = 0; dt < 4; ++dt) {
            const int d = 16 * dt + col16;
            bhalf4 av = *(const bhalf4*)&Vt[d * 64 + ((ch ^ (d & 7)) * 8) + (quad & 1) * 4];
            oT[dt] = __builtin_amdgcn_mfma_f32_16x16x16bf16_1k(av, pb[n], oT[dt], 0, 0, 0);
        }
    }
}

__global__ __launch_bounds__(256) void attn_mfma(
    const unsigned short* __restrict__ qkv,
    const unsigned short* __restrict__ vT,
    unsigned short* __restrict__ yout)
{
    __shared__ unsigned short Ks[64 * 64];
    __shared__ unsigned short Vt[64 * 64];

    const int tid   = threadIdx.x;
    const int wave  = tid >> 6;
    const int col16 = tid & 15;
    const int quad  = (tid & 63) >> 4;
    const int qb    = (int)gridDim.y - 1 - (int)blockIdx.y;  // longest first
    const int bh    = blockIdx.x;
    const int b     = bh >> 4;
    const int h     = bh & 15;

    const unsigned short* base  = qkv + (size_t)b * TSEQ * 3072 + h * 64;
    const unsigned short* kbase = base + CDIM;
    const unsigned short* vtb   = vT + (size_t)(b * 1024 + h * 64) * 2048;

    // Q fragments, loaded once (B-layout for S^T): lane holds
    // Q[q = wave*16+col16][d = ks*32 + quad*8 + j]
    bhalf8 qf[2];
    {
        const unsigned short* qrow =
            base + (size_t)(qb * 64 + wave * 16 + col16) * 3072 + quad * 8;
        qf[0] = *(const bhalf8*)qrow;
        qf[1] = *(const bhalf8*)(qrow + 32);
    }

    floatx4 oT[4];
#pragma unroll
    for (int dt = 0; dt < 4; ++dt) oT[dt] = fx4_zero();
    float l_part = 0.f;
    const int qloc = wave * 16 + col16;

    for (int kb = 0; kb < qb; ++kb)
        attn_kv_tile<false>(kb, kbase, vtb, Ks, Vt, qf, oT, l_part,
                            tid, col16, quad, qloc);
    attn_kv_tile<true>(qb, kbase, vtb, Ks, Vt, qf, oT, l_part,
                       tid, col16, quad, qloc);

    // ---- epilogue: reduce l across quads, O^T/l, store packed bf16 ----
    float l = l_part;
    l += __shfl_xor(l, 16);
    l += __shfl_xor(l, 32);
    const float inv = 1.0f / l;
    const size_t row = (size_t)b * TSEQ + (size_t)qb * 64 + wave * 16 + col16;
#pragma unroll
    for (int dt = 0; dt < 4; ++dt) {
        ushort4 o;
        o.x = f2bf(oT[dt][0] * inv);
        o.y = f2bf(oT[dt][1] * inv);
        o.z = f2bf(oT[dt][2] * inv);
        o.w = f2bf(oT[dt][3] * inv);
        *(ushort4*)(yout + row * CDIM + h * 64 + 16 * dt + quad * 4) = o;
    }
}

// ---------------------------------------------------------------------------
extern "C" void kernel_launch(void* const* d_in, const int* in_sizes, int n_in,
                              void* d_out, int out_size, void* d_ws, size_t ws_size,
                              hipStream_t stream)
{
    const float* x      = (const float*)d_in[0];   // [2,2048,1024]
    const float* W_attn = (const float*)d_in[1];   // [1024,3072]
    const float* b_attn = (const float*)d_in[2];   // [3072]
    const float* W_proj = (const float*)d_in[3];   // [1024,1024]
    const float* b_proj = (const float*)d_in[4];   // [1024]
    float* out = (float*)d_out;                    // [2,2048,1024] fp32

    unsigned short* qkv = (unsigned short*)d_ws;             // bf16 [4096,3072] (V third unused)
    unsigned short* y   = qkv + (size_t)4096 * 3072;         // bf16 [4096,1024]
    unsigned short* xb  = y   + (size_t)4096 * 1024;         // bf16 [4096,1024]
    unsigned short* WtA = xb  + (size_t)4096 * 1024;         // bf16 [3072,1024]
    unsigned short* WtP = WtA + (size_t)3072 * 1024;         // bf16 [1024,1024]
    unsigned short* vT  = WtP + (size_t)1024 * 1024;         // bf16 [2048,2048] V^T

    conv_bf16<<<dim3((4096 * 1024) / (256 * 8)), 256, 0, stream>>>(x, xb);
    transpose_bf16<<<dim3(3072 / 32, 1024 / 32), 256, 0, stream>>>(W_attn, WtA, 1024, 3072);
    transpose_bf16<<<dim3(1024 / 32, 1024 / 32), 256, 0, stream>>>(W_proj, WtP, 1024, 1024);

    // 1) qkv = bf16(x @ W_attn + b_attn); V third written transposed to vT
    gemm_bt<true><<<dim3(3072 / 128, 4096 / 128), 256, 0, stream>>>(
        xb, WtA, b_attn, qkv, 4096, 3072, 1024, 2048, vT);
    // 2) flash attention -> y bf16 [4096,1024]
    attn_mfma<<<dim3(BSZ * HNUM, TSEQ / 64), 256, 0, stream>>>(qkv, vT, y);
    // 3) out = y @ W_proj + b_proj (fp32)
    gemm_bt<false><<<dim3(1024 / 128, 4096 / 128), 256, 0, stream>>>(
        y, WtP, b_proj, out, 4096, 1024, 1024, -1, nullptr);
}

// Round 6
// 198.123 us; speedup vs baseline: 1.0381x; 1.0381x over previous
//
#include <hip/hip_runtime.h>
#include <math.h>

#define BSZ 2
#define TSEQ 2048
#define CDIM 1024
#define HNUM 16

typedef __attribute__((ext_vector_type(8))) short bhalf8;
typedef __attribute__((ext_vector_type(4))) short bhalf4;
typedef __attribute__((ext_vector_type(4))) float floatx4;

__device__ __forceinline__ unsigned short f2bf(float f) {
    union { float f; unsigned u; } v;
    v.f = f;
    unsigned r = v.u + 0x7FFFu + ((v.u >> 16) & 1u);
    return (unsigned short)(r >> 16);
}

__device__ __forceinline__ floatx4 fx4_zero() { floatx4 z = {0.f,0.f,0.f,0.f}; return z; }

// async global->LDS, 16 B per lane. lds dest = (wave-uniform base) + lane*16.
typedef __attribute__((address_space(3))) unsigned int lds_u32;
typedef const __attribute__((address_space(1))) unsigned int g_u32;
__device__ __forceinline__ void async_copy16(const void* g, void* l) {
    __builtin_amdgcn_global_load_lds((g_u32*)g, (lds_u32*)l, 16, 0, 0);
}

// ---------------------------------------------------------------------------
// Prepass: fp32 -> bf16 elementwise (x). 8 elements/thread.
// ---------------------------------------------------------------------------
__global__ __launch_bounds__(256) void conv_bf16(
    const float* __restrict__ x, unsigned short* __restrict__ xb)
{
    size_t i = ((size_t)blockIdx.x * 256 + threadIdx.x) * 8;
    float4 a = *(const float4*)(x + i);
    float4 b = *(const float4*)(x + i + 4);
    uint4 o;
    o.x = (unsigned)f2bf(a.x) | ((unsigned)f2bf(a.y) << 16);
    o.y = (unsigned)f2bf(a.z) | ((unsigned)f2bf(a.w) << 16);
    o.z = (unsigned)f2bf(b.x) | ((unsigned)f2bf(b.y) << 16);
    o.w = (unsigned)f2bf(b.z) | ((unsigned)f2bf(b.w) << 16);
    *(uint4*)(xb + i) = o;
}

// ---------------------------------------------------------------------------
// Prepass: W [K,N] fp32 -> Wt [N,K] bf16 (transpose + convert). 32x32 tiles.
// ---------------------------------------------------------------------------
__global__ __launch_bounds__(256) void transpose_bf16(
    const float* __restrict__ W, unsigned short* __restrict__ Wt, int K, int N)
{
    __shared__ float t[32][33];
    const int n0 = blockIdx.x * 32, k0 = blockIdx.y * 32;
    const int tx = threadIdx.x & 31, ty = threadIdx.x >> 5;
#pragma unroll
    for (int i = 0; i < 4; ++i)
        t[ty + i * 8][tx] = W[(size_t)(k0 + ty + i * 8) * N + n0 + tx];
    __syncthreads();
#pragma unroll
    for (int i = 0; i < 4; ++i)
        Wt[(size_t)(n0 + ty + i * 8) * K + k0 + tx] = f2bf(t[tx][ty + i * 8]);
}

// ---------------------------------------------------------------------------
// V^T kernel: qkv V-slice [b*2048+t][2048 + c] -> vT[b*1024 + c][t].
// 64x64 tiles through LDS; coalesced 16-B loads and stores.
// ---------------------------------------------------------------------------
__global__ __launch_bounds__(256) void vtrans(
    const unsigned short* __restrict__ qkv, unsigned short* __restrict__ vT)
{
    __shared__ unsigned short tt[64][80];   // [c-local][t-local], pitch 80
    const int b  = blockIdx.z;
    const int ty = blockIdx.y * 64;   // t tile
    const int cx = blockIdx.x * 64;   // V col tile
    const int tid = threadIdx.x;
    const int lr = tid >> 2, lc = (tid & 3) * 16;

    const unsigned short* src =
        qkv + (size_t)(b * 2048 + ty + lr) * 3072 + 2048 + cx + lc;
    uint4 v0 = *(const uint4*)src;
    uint4 v1 = *(const uint4*)(src + 8);
    tt[lc + 0][lr]  = (unsigned short)(v0.x & 0xffff);
    tt[lc + 1][lr]  = (unsigned short)(v0.x >> 16);
    tt[lc + 2][lr]  = (unsigned short)(v0.y & 0xffff);
    tt[lc + 3][lr]  = (unsigned short)(v0.y >> 16);
    tt[lc + 4][lr]  = (unsigned short)(v0.z & 0xffff);
    tt[lc + 5][lr]  = (unsigned short)(v0.z >> 16);
    tt[lc + 6][lr]  = (unsigned short)(v0.w & 0xffff);
    tt[lc + 7][lr]  = (unsigned short)(v0.w >> 16);
    tt[lc + 8][lr]  = (unsigned short)(v1.x & 0xffff);
    tt[lc + 9][lr]  = (unsigned short)(v1.x >> 16);
    tt[lc + 10][lr] = (unsigned short)(v1.y & 0xffff);
    tt[lc + 11][lr] = (unsigned short)(v1.y >> 16);
    tt[lc + 12][lr] = (unsigned short)(v1.z & 0xffff);
    tt[lc + 13][lr] = (unsigned short)(v1.z >> 16);
    tt[lc + 14][lr] = (unsigned short)(v1.w & 0xffff);
    tt[lc + 15][lr] = (unsigned short)(v1.w >> 16);
    __syncthreads();
    unsigned short* dst = vT + (size_t)(b * 1024 + cx + lr) * 2048 + ty + lc;
    *(uint4*)dst       = *(const uint4*)&tt[lr][lc];
    *(uint4*)(dst + 8) = *(const uint4*)&tt[lr][lc + 8];
}

// ---------------------------------------------------------------------------
// bf16 MFMA GEMM (B^T input) + bias, single-barrier double-buffered K-loop.
// C[M,N] = A[M,K] @ Bt[N,K]^T + bias[N].  Block tile BM x 128, BK=32,
// 256 threads (4 waves). BM=128: wave 64x64 (4x4 tiles); BM=64: 32x64 (2x4).
// Per iter: stage(k+1 -> nxt) BEFORE compute(cur); one __syncthreads at end
// (its vmcnt(0) drain lands after compute -> fetch overlaps MFMA).
// ---------------------------------------------------------------------------
template<int BM, bool OUT_BF16>
__global__ __launch_bounds__(256) void gemm_bt(
    const unsigned short* __restrict__ A, const unsigned short* __restrict__ Bt,
    const float* __restrict__ bias, void* __restrict__ Cp,
    int M, int N, int K)
{
    constexpr int ALINES = BM / 64;
    constexpr int MT = BM / 32;
    __shared__ unsigned short As[2][BM * 32];
    __shared__ unsigned short Bs[2][128 * 32];

    const int tid   = threadIdx.x;
    const int bm    = blockIdx.y;
    const int bn    = blockIdx.x;
    const int wave  = tid >> 6;
    const int col16 = tid & 15;
    const int quad  = (tid & 63) >> 4;
    const int wm    = (wave >> 1) * (BM / 2);
    const int wn    = (wave & 1) * 64;

    floatx4 acc[MT][4];
#pragma unroll
    for (int i = 0; i < MT; ++i)
#pragma unroll
        for (int j = 0; j < 4; ++j) acc[i][j] = fx4_zero();

    const int gr = tid >> 2;
    const int gk = (tid & 3) * 8;
    const unsigned short* Ab = A  + (size_t)(bm * BM + gr) * K + gk;
    const unsigned short* Bb = Bt + (size_t)(bn * 128 + gr) * K + gk;

#define STAGE(k0, bf) { \
    char* AsB = (char*)As[bf] + wave * 1024; \
    char* BsB = (char*)Bs[bf] + wave * 1024; \
    _Pragma("unroll") \
    for (int l = 0; l < ALINES; ++l) \
        async_copy16(Ab + (size_t)l * 64 * K + (k0), AsB + l * 4096); \
    async_copy16(Bb + (k0), BsB); \
    async_copy16(Bb + (size_t)64 * K + (k0), BsB + 4096); }

#define COMPUTE(bf) { \
    bhalf8 a[MT], b[4]; \
    _Pragma("unroll") \
    for (int i = 0; i < MT; ++i) \
        a[i] = *(const bhalf8*)&As[bf][(wm + i * 16 + col16) * 32 + quad * 8]; \
    _Pragma("unroll") \
    for (int j = 0; j < 4; ++j) \
        b[j] = *(const bhalf8*)&Bs[bf][(wn + j * 16 + col16) * 32 + quad * 8]; \
    _Pragma("unroll") \
    for (int i = 0; i < MT; ++i) \
        _Pragma("unroll") \
        for (int j = 0; j < 4; ++j) \
            acc[i][j] = __builtin_amdgcn_mfma_f32_16x16x32_bf16(a[i], b[j], acc[i][j], 0, 0, 0); }

    STAGE(0, 0);
    __syncthreads();
    int buf = 0;
    for (int k0 = 0; k0 < K - 32; k0 += 32) {
        STAGE(k0 + 32, buf ^ 1);
        COMPUTE(buf);
        __syncthreads();
        buf ^= 1;
    }
    COMPUTE(buf);
#undef STAGE
#undef COMPUTE

#pragma unroll
    for (int j = 0; j < 4; ++j) {
        int col = bn * 128 + wn + j * 16 + col16;
        float bv = bias[col];
#pragma unroll
        for (int i = 0; i < MT; ++i) {
#pragma unroll
            for (int r = 0; r < 4; ++r) {
                int row = bm * BM + wm + i * 16 + quad * 4 + r;
                float v = acc[i][j][r] + bv;
                if (OUT_BF16)
                    ((unsigned short*)Cp)[(size_t)row * N + col] = f2bf(v);
                else
                    ((float*)Cp)[(size_t)row * N + col] = v;
            }
        }
    }
}

// ---------------------------------------------------------------------------
// MFMA flash attention v4: transposed scores, P in registers, double-buffered
// single-barrier KV loop, conflict-free unit-preserving Vt layout.
//   S^T = K.Q^T (16x16x32);  O^T = V^T.P^T (16x16x16, P^T direct from regs)
// Fixed-shift softmax p = exp(s/8 - 12); l reduced once at epilogue.
// K image:  row*128B + ((chunk ^ (row&7))*16B)           (b128 reads, free)
// Vt image: 32-B units kept intact: unit(d,n) at n*64 + ((d+n)&63).
//   PV read = quad-contiguous 32 B per col16 -> merges, 4 octets/cycle.
// ---------------------------------------------------------------------------
template<bool DIAG>
__device__ __forceinline__ void attn_tile(
    const unsigned short* __restrict__ Ks, const unsigned short* __restrict__ Vt,
    const bhalf8* qf, floatx4* oT, float& l_part,
    int col16, int quad, int qloc)
{
    const float C_MUL = 0.125f * 1.44269504f;   // exp(s/8-12) = exp2(s*c - c2)
    const float C_SUB = 17.31234049f;
    const int sx = col16 & 7;

    floatx4 s[4];
#pragma unroll
    for (int n = 0; n < 4; ++n) {
        const int row = 16 * n + col16;
        bhalf8 k0 = *(const bhalf8*)&Ks[row * 64 + ((quad ^ sx) * 8)];
        bhalf8 k1 = *(const bhalf8*)&Ks[row * 64 + (((4 + quad) ^ sx) * 8)];
        floatx4 t = __builtin_amdgcn_mfma_f32_16x16x32_bf16(k0, qf[0], fx4_zero(), 0, 0, 0);
        s[n] = __builtin_amdgcn_mfma_f32_16x16x32_bf16(k1, qf[1], t, 0, 0, 0);
    }

    bhalf4 pb[4];
#pragma unroll
    for (int n = 0; n < 4; ++n) {
        unsigned a[4];
#pragma unroll
        for (int r = 0; r < 4; ++r) {
            float p = exp2f(fmaf(s[n][r], C_MUL, -C_SUB));
            if (DIAG) {
                if (16 * n + quad * 4 + r > qloc) p = 0.f;
            }
            l_part += p;
            a[r] = __float_as_uint(p) + 0x8000u;   // bias-round to bf16
        }
        union { unsigned u[2]; bhalf4 b; } uu;
        uu.u[0] = (a[0] >> 16) | (a[1] & 0xffff0000u);
        uu.u[1] = (a[2] >> 16) | (a[3] & 0xffff0000u);
        pb[n] = uu.b;
    }

#pragma unroll
    for (int n = 0; n < 4; ++n) {
#pragma unroll
        for (int dt = 0; dt < 4; ++dt) {
            const int d = 16 * dt + col16;
            const bhalf4 av = *(const bhalf4*)
                &Vt[n * 1024 + ((d + n) & 63) * 16 + (quad >> 1) * 8 + (quad & 1) * 4];
            oT[dt] = __builtin_amdgcn_mfma_f32_16x16x16bf16_1k(av, pb[n], oT[dt], 0, 0, 0);
        }
    }
}

__global__ __launch_bounds__(256) void attn_mfma(
    const unsigned short* __restrict__ qkv,
    const unsigned short* __restrict__ vT,
    unsigned short* __restrict__ yout)
{
    __shared__ unsigned short Kbuf[2][64 * 64];
    __shared__ unsigned short Vbuf[2][64 * 64];

    const int tid   = threadIdx.x;
    const int wave  = tid >> 6;
    const int col16 = tid & 15;
    const int quad  = (tid & 63) >> 4;
    const int qb    = (int)gridDim.y - 1 - (int)blockIdx.y;  // longest first
    const int bh    = blockIdx.x;
    const int b     = bh >> 4;
    const int h     = bh & 15;

    const unsigned short* base  = qkv + (size_t)b * TSEQ * 3072 + h * 64;
    const unsigned short* kbase = base + CDIM;
    const unsigned short* vtb   = vT + (size_t)(b * 1024 + h * 64) * 2048;

    // Q fragments (B-layout for S^T): lane holds Q[q=wave*16+col16][d=quad*8+j]
    bhalf8 qf[2];
    {
        const unsigned short* qrow =
            base + (size_t)(qb * 64 + wave * 16 + col16) * 3072 + quad * 8;
        qf[0] = *(const bhalf8*)qrow;
        qf[1] = *(const bhalf8*)(qrow + 32);
    }

    // K staging map: lane covers K row (tid>>3)+32*call, chunk (tid&7)^(row&7)
    const int krow = tid >> 3;
    const int kchk = (tid & 7) ^ (krow & 7);
    const unsigned short* ksrc0 = kbase + (size_t)krow * 3072 + kchk * 8;
    const unsigned short* ksrc1 = kbase + (size_t)(krow + 32) * 3072 + kchk * 8;

    // V staging map (unit-preserving): linear cell L -> content:
    //   h=L&1, u=L>>1, n=u>>6, d=((u&63)-n)&63, chunk c=2n+h
    int L0 = tid, L1 = tid + 256;
    const int d0 = (((L0 >> 1) & 63) - ((L0 >> 1) >> 6)) & 63;
    const int c0 = 2 * ((L0 >> 1) >> 6) + (L0 & 1);
    const int d1 = (((L1 >> 1) & 63) - ((L1 >> 1) >> 6)) & 63;
    const int c1 = 2 * ((L1 >> 1) >> 6) + (L1 & 1);
    const unsigned short* vsrc0 = vtb + (size_t)d0 * 2048 + c0 * 8;
    const unsigned short* vsrc1 = vtb + (size_t)d1 * 2048 + c1 * 8;

#define ASTAGE(kb, bf) { \
    char* Kd = (char*)Kbuf[bf] + wave * 1024; \
    char* Vd = (char*)Vbuf[bf] + wave * 1024; \
    async_copy16(ksrc0 + (size_t)(kb) * 64 * 3072, Kd); \
    async_copy16(ksrc1 + (size_t)(kb) * 64 * 3072, Kd + 4096); \
    async_copy16(vsrc0 + (kb) * 64, Vd); \
    async_copy16(vsrc1 + (kb) * 64, Vd + 4096); }

    floatx4 oT[4];
#pragma unroll
    for (int dt = 0; dt < 4; ++dt) oT[dt] = fx4_zero();
    float l_part = 0.f;
    const int qloc = wave * 16 + col16;

    ASTAGE(0, 0);
    __syncthreads();
    int buf = 0;
    for (int kb = 0; kb < qb; ++kb) {
        ASTAGE(kb + 1, buf ^ 1);
        attn_tile<false>(Kbuf[buf], Vbuf[buf], qf, oT, l_part, col16, quad, qloc);
        __syncthreads();
        buf ^= 1;
    }
    attn_tile<true>(Kbuf[buf], Vbuf[buf], qf, oT, l_part, col16, quad, qloc);
#undef ASTAGE

    // epilogue: reduce l across quads, O^T/l, store packed bf16
    float l = l_part;
    l += __shfl_xor(l, 16);
    l += __shfl_xor(l, 32);
    const float inv = 1.0f / l;
    const size_t row = (size_t)b * TSEQ + (size_t)qb * 64 + wave * 16 + col16;
#pragma unroll
    for (int dt = 0; dt < 4; ++dt) {
        ushort4 o;
        o.x = f2bf(oT[dt][0] * inv);
        o.y = f2bf(oT[dt][1] * inv);
        o.z = f2bf(oT[dt][2] * inv);
        o.w = f2bf(oT[dt][3] * inv);
        *(ushort4*)(yout + row * CDIM + h * 64 + 16 * dt + quad * 4) = o;
    }
}

// ---------------------------------------------------------------------------
extern "C" void kernel_launch(void* const* d_in, const int* in_sizes, int n_in,
                              void* d_out, int out_size, void* d_ws, size_t ws_size,
                              hipStream_t stream)
{
    const float* x      = (const float*)d_in[0];   // [2,2048,1024]
    const float* W_attn = (const float*)d_in[1];   // [1024,3072]
    const float* b_attn = (const float*)d_in[2];   // [3072]
    const float* W_proj = (const float*)d_in[3];   // [1024,1024]
    const float* b_proj = (const float*)d_in[4];   // [1024]
    float* out = (float*)d_out;                    // [2,2048,1024] fp32

    unsigned short* qkv = (unsigned short*)d_ws;             // bf16 [4096,3072]
    unsigned short* y   = qkv + (size_t)4096 * 3072;         // bf16 [4096,1024]
    unsigned short* xb  = y   + (size_t)4096 * 1024;         // bf16 [4096,1024]
    unsigned short* WtA = xb  + (size_t)4096 * 1024;         // bf16 [3072,1024]
    unsigned short* WtP = WtA + (size_t)3072 * 1024;         // bf16 [1024,1024]
    unsigned short* vT  = WtP + (size_t)1024 * 1024;         // bf16 [2048,2048]

    conv_bf16<<<dim3((4096 * 1024) / (256 * 8)), 256, 0, stream>>>(x, xb);
    transpose_bf16<<<dim3(3072 / 32, 1024 / 32), 256, 0, stream>>>(W_attn, WtA, 1024, 3072);
    transpose_bf16<<<dim3(1024 / 32, 1024 / 32), 256, 0, stream>>>(W_proj, WtP, 1024, 1024);

    // 1) qkv = bf16(x @ W_attn + b_attn)   M=4096 N=3072 K=1024
    gemm_bt<128, true><<<dim3(3072 / 128, 4096 / 128), 256, 0, stream>>>(
        xb, WtA, b_attn, qkv, 4096, 3072, 1024);
    // 2) V^T for attention
    vtrans<<<dim3(16, 32, 2), 256, 0, stream>>>(qkv, vT);
    // 3) flash attention -> y bf16 [4096,1024]
    attn_mfma<<<dim3(BSZ * HNUM, TSEQ / 64), 256, 0, stream>>>(qkv, vT, y);
    // 4) out = y @ W_proj + b_proj (fp32)  M=4096 N=1024 K=1024, 64-row tiles
    gemm_bt<64, false><<<dim3(1024 / 128, 4096 / 64), 256, 0, stream>>>(
        y, WtP, b_proj, out, 4096, 1024, 1024);
}

// Round 7
// 188.418 us; speedup vs baseline: 1.0916x; 1.0515x over previous
//
#include <hip/hip_runtime.h>
#include <math.h>

#define BSZ 2
#define TSEQ 2048
#define CDIM 1024
#define HNUM 16

typedef __attribute__((ext_vector_type(8))) short bhalf8;
typedef __attribute__((ext_vector_type(4))) short bhalf4;
typedef __attribute__((ext_vector_type(4))) float floatx4;

__device__ __forceinline__ unsigned short f2bf(float f) {
    union { float f; unsigned u; } v;
    v.f = f;
    unsigned r = v.u + 0x7FFFu + ((v.u >> 16) & 1u);
    return (unsigned short)(r >> 16);
}

__device__ __forceinline__ floatx4 fx4_zero() { floatx4 z = {0.f,0.f,0.f,0.f}; return z; }

// async global->LDS, 16 B per lane. lds dest = (wave-uniform base) + lane*16.
typedef __attribute__((address_space(3))) unsigned int lds_u32;
typedef const __attribute__((address_space(1))) unsigned int g_u32;
__device__ __forceinline__ void async_copy16(const void* g, void* l) {
    __builtin_amdgcn_global_load_lds((g_u32*)g, (lds_u32*)l, 16, 0, 0);
}

// ---------------------------------------------------------------------------
// Prepass: fp32 -> bf16 elementwise (x). 8 elements/thread.
// ---------------------------------------------------------------------------
__global__ __launch_bounds__(256) void conv_bf16(
    const float* __restrict__ x, unsigned short* __restrict__ xb)
{
    size_t i = ((size_t)blockIdx.x * 256 + threadIdx.x) * 8;
    float4 a = *(const float4*)(x + i);
    float4 b = *(const float4*)(x + i + 4);
    uint4 o;
    o.x = (unsigned)f2bf(a.x) | ((unsigned)f2bf(a.y) << 16);
    o.y = (unsigned)f2bf(a.z) | ((unsigned)f2bf(a.w) << 16);
    o.z = (unsigned)f2bf(b.x) | ((unsigned)f2bf(b.y) << 16);
    o.w = (unsigned)f2bf(b.z) | ((unsigned)f2bf(b.w) << 16);
    *(uint4*)(xb + i) = o;
}

// ---------------------------------------------------------------------------
// Prepass: W [K,N] fp32 -> Wt [N,K] bf16 (transpose + convert). 32x32 tiles.
// ---------------------------------------------------------------------------
__global__ __launch_bounds__(256) void transpose_bf16(
    const float* __restrict__ W, unsigned short* __restrict__ Wt, int K, int N)
{
    __shared__ float t[32][33];
    const int n0 = blockIdx.x * 32, k0 = blockIdx.y * 32;
    const int tx = threadIdx.x & 31, ty = threadIdx.x >> 5;
#pragma unroll
    for (int i = 0; i < 4; ++i)
        t[ty + i * 8][tx] = W[(size_t)(k0 + ty + i * 8) * N + n0 + tx];
    __syncthreads();
#pragma unroll
    for (int i = 0; i < 4; ++i)
        Wt[(size_t)(n0 + ty + i * 8) * K + k0 + tx] = f2bf(t[tx][ty + i * 8]);
}

// ---------------------------------------------------------------------------
// bf16 MFMA GEMM (B^T input) + bias, single-barrier double-buffered K-loop.
// C[M,N] = A[M,K] @ Bt[N,K]^T + bias[N].  Block tile BM x 128, BK=32,
// 256 threads (4 waves). BM=128: wave 64x64 (4x4); BM=64: 32x64 (2x4).
// Blocks whose colbase >= v_start write TRANSPOSED to vt via ushort4:
// C-layout gives each lane 4 consecutive rows (t) for one col (d) = one
// 8-B chunk of vT row d. vt layout: [ (row>>11)*1024 + (col-v_start) ][ t ].
// ---------------------------------------------------------------------------
template<int BM, bool OUT_BF16>
__global__ __launch_bounds__(256) void gemm_bt(
    const unsigned short* __restrict__ A, const unsigned short* __restrict__ Bt,
    const float* __restrict__ bias, void* __restrict__ Cp,
    int M, int N, int K, int v_start, unsigned short* __restrict__ vt)
{
    constexpr int ALINES = BM / 64;
    constexpr int MT = BM / 32;
    __shared__ unsigned short As[2][BM * 32];
    __shared__ unsigned short Bs[2][128 * 32];

    const int tid   = threadIdx.x;
    const int bm    = blockIdx.y;
    const int bn    = blockIdx.x;
    const int wave  = tid >> 6;
    const int col16 = tid & 15;
    const int quad  = (tid & 63) >> 4;
    const int wm    = (wave >> 1) * (BM / 2);
    const int wn    = (wave & 1) * 64;

    floatx4 acc[MT][4];
#pragma unroll
    for (int i = 0; i < MT; ++i)
#pragma unroll
        for (int j = 0; j < 4; ++j) acc[i][j] = fx4_zero();

    const int gr = tid >> 2;
    const int gk = (tid & 3) * 8;
    const unsigned short* Ab = A  + (size_t)(bm * BM + gr) * K + gk;
    const unsigned short* Bb = Bt + (size_t)(bn * 128 + gr) * K + gk;

#define STAGE(k0, bf) { \
    char* AsB = (char*)As[bf] + wave * 1024; \
    char* BsB = (char*)Bs[bf] + wave * 1024; \
    _Pragma("unroll") \
    for (int l = 0; l < ALINES; ++l) \
        async_copy16(Ab + (size_t)l * 64 * K + (k0), AsB + l * 4096); \
    async_copy16(Bb + (k0), BsB); \
    async_copy16(Bb + (size_t)64 * K + (k0), BsB + 4096); }

#define COMPUTE(bf) { \
    bhalf8 a[MT], b[4]; \
    _Pragma("unroll") \
    for (int i = 0; i < MT; ++i) \
        a[i] = *(const bhalf8*)&As[bf][(wm + i * 16 + col16) * 32 + quad * 8]; \
    _Pragma("unroll") \
    for (int j = 0; j < 4; ++j) \
        b[j] = *(const bhalf8*)&Bs[bf][(wn + j * 16 + col16) * 32 + quad * 8]; \
    _Pragma("unroll") \
    for (int i = 0; i < MT; ++i) \
        _Pragma("unroll") \
        for (int j = 0; j < 4; ++j) \
            acc[i][j] = __builtin_amdgcn_mfma_f32_16x16x32_bf16(a[i], b[j], acc[i][j], 0, 0, 0); }

    STAGE(0, 0);
    __syncthreads();
    int buf = 0;
    for (int k0 = 0; k0 < K - 32; k0 += 32) {
        STAGE(k0 + 32, buf ^ 1);
        COMPUTE(buf);
        __syncthreads();
        buf ^= 1;
    }
    COMPUTE(buf);
#undef STAGE
#undef COMPUTE

    const int colbase = bn * 128 + wn;
    const bool vpath = (v_start >= 0) && (colbase >= v_start);  // wave-uniform
#pragma unroll
    for (int j = 0; j < 4; ++j) {
        int col = colbase + j * 16 + col16;
        float bv = bias[col];
#pragma unroll
        for (int i = 0; i < MT; ++i) {
            if (vpath) {
                int row0 = bm * BM + wm + i * 16 + quad * 4;
                ushort4 o;
                o.x = f2bf(acc[i][j][0] + bv);
                o.y = f2bf(acc[i][j][1] + bv);
                o.z = f2bf(acc[i][j][2] + bv);
                o.w = f2bf(acc[i][j][3] + bv);
                size_t vrow = (size_t)((row0 >> 11) * 1024 + (col - v_start));
                *(ushort4*)(vt + vrow * 2048 + (row0 & 2047)) = o;
            } else {
#pragma unroll
                for (int r = 0; r < 4; ++r) {
                    int row = bm * BM + wm + i * 16 + quad * 4 + r;
                    float v = acc[i][j][r] + bv;
                    if (OUT_BF16)
                        ((unsigned short*)Cp)[(size_t)row * N + col] = f2bf(v);
                    else
                        ((float*)Cp)[(size_t)row * N + col] = v;
                }
            }
        }
    }
}

// ---------------------------------------------------------------------------
// MFMA flash attention v5: transposed scores, P in registers, double-buffered
// single-barrier KV loop.
//   S^T = K.Q^T (16x16x32);  O^T = V^T.P^T (16x16x16, P^T direct from regs)
// Fixed-shift softmax p = exp(s/8 - 12); l reduced once at epilogue.
// K image:  row*128B + (chunk ^ (row&7))*16B   (async-staged; b128 reads:
//   8-lane phase covers 8 distinct bank-quads -> conflict-free)
// V image:  Vt[d*76 + t]  (pitch 76 shorts). Staged with explicit global
//   b128 loads + ds_write_b128 (8-lane write phase: d fixed, 8 distinct
//   bank-starts -> free). PV b64 read phase: bank start = (38d) mod 32 =
//   6*col16 -> 16 distinct even residues -> conflict-free (R4-proven).
// ---------------------------------------------------------------------------
template<bool DIAG>
__device__ __forceinline__ void attn_tile(
    const unsigned short* __restrict__ Ks, const unsigned short* __restrict__ Vt,
    const bhalf8* qf, floatx4* oT, float& l_part,
    int col16, int quad, int qloc)
{
    const float C_MUL = 0.125f * 1.44269504f;   // exp(s/8-12) = exp2(s*c - c2)
    const float C_SUB = 17.31234049f;
    const int sx = col16 & 7;

    floatx4 s[4];
#pragma unroll
    for (int n = 0; n < 4; ++n) {
        const int row = 16 * n + col16;
        bhalf8 k0 = *(const bhalf8*)&Ks[row * 64 + ((quad ^ sx) * 8)];
        bhalf8 k1 = *(const bhalf8*)&Ks[row * 64 + (((4 + quad) ^ sx) * 8)];
        floatx4 t = __builtin_amdgcn_mfma_f32_16x16x32_bf16(k0, qf[0], fx4_zero(), 0, 0, 0);
        s[n] = __builtin_amdgcn_mfma_f32_16x16x32_bf16(k1, qf[1], t, 0, 0, 0);
    }

    bhalf4 pb[4];
#pragma unroll
    for (int n = 0; n < 4; ++n) {
        unsigned a[4];
#pragma unroll
        for (int r = 0; r < 4; ++r) {
            float p = exp2f(fmaf(s[n][r], C_MUL, -C_SUB));
            if (DIAG) {
                if (16 * n + quad * 4 + r > qloc) p = 0.f;
            }
            l_part += p;
            a[r] = __float_as_uint(p) + 0x8000u;   // bias-round to bf16
        }
        union { unsigned u[2]; bhalf4 b; } uu;
        uu.u[0] = (a[0] >> 16) | (a[1] & 0xffff0000u);
        uu.u[1] = (a[2] >> 16) | (a[3] & 0xffff0000u);
        pb[n] = uu.b;
    }

#pragma unroll
    for (int n = 0; n < 4; ++n) {
#pragma unroll
        for (int dt = 0; dt < 4; ++dt) {
            const int d = 16 * dt + col16;
            const bhalf4 av = *(const bhalf4*)&Vt[d * 76 + 16 * n + quad * 4];
            oT[dt] = __builtin_amdgcn_mfma_f32_16x16x16bf16_1k(av, pb[n], oT[dt], 0, 0, 0);
        }
    }
}

__global__ __launch_bounds__(256) void attn_mfma(
    const unsigned short* __restrict__ qkv,
    const unsigned short* __restrict__ vT,
    unsigned short* __restrict__ yout)
{
    __shared__ unsigned short Kbuf[2][64 * 64];
    __shared__ unsigned short Vbuf[2][64 * 76];

    const int tid   = threadIdx.x;
    const int wave  = tid >> 6;
    const int col16 = tid & 15;
    const int quad  = (tid & 63) >> 4;
    const int qb    = (int)gridDim.y - 1 - (int)blockIdx.y;  // longest first
    const int bh    = blockIdx.x;
    const int b     = bh >> 4;
    const int h     = bh & 15;

    const unsigned short* base  = qkv + (size_t)b * TSEQ * 3072 + h * 64;
    const unsigned short* kbase = base + CDIM;
    const unsigned short* vtb   = vT + (size_t)(b * 1024 + h * 64) * 2048;

    // Q fragments (B-layout for S^T): lane holds Q[q=wave*16+col16][d=quad*8+j]
    bhalf8 qf[2];
    {
        const unsigned short* qrow =
            base + (size_t)(qb * 64 + wave * 16 + col16) * 3072 + quad * 8;
        qf[0] = *(const bhalf8*)qrow;
        qf[1] = *(const bhalf8*)(qrow + 32);
    }

    // K staging map: lane covers K row (tid>>3)(+32), chunk (tid&7)^(row&7)
    const int krow = tid >> 3;
    const int kchk = (tid & 7) ^ (krow & 7);
    const unsigned short* ksrc0 = kbase + (size_t)krow * 3072 + kchk * 8;
    const unsigned short* ksrc1 = kbase + (size_t)(krow + 32) * 3072 + kchk * 8;

    // V staging map: lane covers vT row d=(tid>>3)(+32), t chunk (tid&7)*8
    const int vd  = tid >> 3;
    const int vt0 = (tid & 7) * 8;
    const unsigned short* vsrc0 = vtb + (size_t)vd * 2048 + vt0;
    const unsigned short* vsrc1 = vtb + (size_t)(vd + 32) * 2048 + vt0;

#define KSTAGE(kb, bf) { \
    char* Kd = (char*)Kbuf[bf] + wave * 1024; \
    async_copy16(ksrc0 + (size_t)(kb) * 64 * 3072, Kd); \
    async_copy16(ksrc1 + (size_t)(kb) * 64 * 3072, Kd + 4096); }

    floatx4 oT[4];
#pragma unroll
    for (int dt = 0; dt < 4; ++dt) oT[dt] = fx4_zero();
    float l_part = 0.f;
    const int qloc = wave * 16 + col16;

    {   // prologue: stage tile 0 into buf 0
        uint4 nv0 = *(const uint4*)vsrc0;
        uint4 nv1 = *(const uint4*)vsrc1;
        KSTAGE(0, 0);
        *(uint4*)&Vbuf[0][vd * 76 + vt0]        = nv0;
        *(uint4*)&Vbuf[0][(vd + 32) * 76 + vt0] = nv1;
    }
    __syncthreads();
    int buf = 0;
    for (int kb = 0; kb < qb; ++kb) {
        uint4 nv0 = *(const uint4*)(vsrc0 + (size_t)(kb + 1) * 64);
        uint4 nv1 = *(const uint4*)(vsrc1 + (size_t)(kb + 1) * 64);
        KSTAGE(kb + 1, buf ^ 1);
        attn_tile<false>(Kbuf[buf], Vbuf[buf], qf, oT, l_part, col16, quad, qloc);
        *(uint4*)&Vbuf[buf ^ 1][vd * 76 + vt0]        = nv0;
        *(uint4*)&Vbuf[buf ^ 1][(vd + 32) * 76 + vt0] = nv1;
        __syncthreads();
        buf ^= 1;
    }
    attn_tile<true>(Kbuf[buf], Vbuf[buf], qf, oT, l_part, col16, quad, qloc);
#undef KSTAGE

    // epilogue: reduce l across quads, O^T/l, store packed bf16
    float l = l_part;
    l += __shfl_xor(l, 16);
    l += __shfl_xor(l, 32);
    const float inv = 1.0f / l;
    const size_t row = (size_t)b * TSEQ + (size_t)qb * 64 + wave * 16 + col16;
#pragma unroll
    for (int dt = 0; dt < 4; ++dt) {
        ushort4 o;
        o.x = f2bf(oT[dt][0] * inv);
        o.y = f2bf(oT[dt][1] * inv);
        o.z = f2bf(oT[dt][2] * inv);
        o.w = f2bf(oT[dt][3] * inv);
        *(ushort4*)(yout + row * CDIM + h * 64 + 16 * dt + quad * 4) = o;
    }
}

// ---------------------------------------------------------------------------
extern "C" void kernel_launch(void* const* d_in, const int* in_sizes, int n_in,
                              void* d_out, int out_size, void* d_ws, size_t ws_size,
                              hipStream_t stream)
{
    const float* x      = (const float*)d_in[0];   // [2,2048,1024]
    const float* W_attn = (const float*)d_in[1];   // [1024,3072]
    const float* b_attn = (const float*)d_in[2];   // [3072]
    const float* W_proj = (const float*)d_in[3];   // [1024,1024]
    const float* b_proj = (const float*)d_in[4];   // [1024]
    float* out = (float*)d_out;                    // [2,2048,1024] fp32

    unsigned short* qkv = (unsigned short*)d_ws;             // bf16 [4096,3072] (V third unused)
    unsigned short* y   = qkv + (size_t)4096 * 3072;         // bf16 [4096,1024]
    unsigned short* xb  = y   + (size_t)4096 * 1024;         // bf16 [4096,1024]
    unsigned short* WtA = xb  + (size_t)4096 * 1024;         // bf16 [3072,1024]
    unsigned short* WtP = WtA + (size_t)3072 * 1024;         // bf16 [1024,1024]
    unsigned short* vT  = WtP + (size_t)1024 * 1024;         // bf16 [2048,2048]

    conv_bf16<<<dim3((4096 * 1024) / (256 * 8)), 256, 0, stream>>>(x, xb);
    transpose_bf16<<<dim3(3072 / 32, 1024 / 32), 256, 0, stream>>>(W_attn, WtA, 1024, 3072);
    transpose_bf16<<<dim3(1024 / 32, 1024 / 32), 256, 0, stream>>>(W_proj, WtP, 1024, 1024);

    // 1) qkv = bf16(x @ W_attn + b_attn); V cols (>=2048) go transposed to vT
    gemm_bt<128, true><<<dim3(3072 / 128, 4096 / 128), 256, 0, stream>>>(
        xb, WtA, b_attn, qkv, 4096, 3072, 1024, 2048, vT);
    // 2) flash attention -> y bf16 [4096,1024]
    attn_mfma<<<dim3(BSZ * HNUM, TSEQ / 64), 256, 0, stream>>>(qkv, vT, y);
    // 3) out = y @ W_proj + b_proj (fp32)  M=4096 N=1024 K=1024, 64-row tiles
    gemm_bt<64, false><<<dim3(1024 / 128, 4096 / 64), 256, 0, stream>>>(
        y, WtP, b_proj, out, 4096, 1024, 1024, -1, nullptr);
}